// Round 1
// baseline (137.439 us; speedup 1.0000x reference)
//
#include <hip/hip_runtime.h>

#define HQ 32
#define HKV 8
#define DH 128
#define WIN 256
#define META 128
#define QSCALE 0.1275174324f    // rsqrt(128) * log2(e)  (scores produced in log2 space)
#define NFREQ 0.20762050594046f // log2(10000)/64: invfreq(i) = exp2(-NFREQ*i)

typedef __attribute__((ext_vector_type(8))) __bf16 bf16x8;
typedef __attribute__((ext_vector_type(4))) float f32x4;
typedef unsigned short u16;
typedef unsigned int u32;

__device__ __forceinline__ u16 f2bf(float f) {
  u32 u = __float_as_uint(f);
  u += 0x7FFFu + ((u >> 16) & 1u);
  return (u16)(u >> 16);
}
__device__ __forceinline__ u32 packbf(float a, float b) {  // a->lo16, b->hi16
  u32 ua = __float_as_uint(a); ua += 0x7FFFu + ((ua >> 16) & 1u);
  u32 ub = __float_as_uint(b); ub += 0x7FFFu + ((ub >> 16) & 1u);
  return (ua >> 16) | (ub & 0xFFFF0000u);
}

// ---------- prep: RoPE(K) -> Kr[hk][s][d] bf16 ; V -> Vt[hk][d][s] bf16 ----------
// 32 s-rows per block (544 blocks: 2x wave parallelism vs 64-row version).
// hk==0 blocks also emit the cos/sin table (f32x2 [s][64]) consumed by attn's Q RoPE.
__global__ __launch_bounds__(256)
void prep_kv(const float* __restrict__ Kg, const float* __restrict__ Vg,
             u16* __restrict__ Kr, u16* __restrict__ Vt, float2* __restrict__ Tab,
             int S) {
  __shared__ float T[32][132];
  const int hk = blockIdx.x;
  const int s0 = blockIdx.y * 32;
  const int tid = threadIdx.x;
  {
    const int r = tid >> 3, c0 = (tid & 7) * 8;
    const int s = s0 + r;
    const float pos = (float)s;
    const float* src = Kg + ((size_t)s * HKV + hk) * DH;
    u16* dst = Kr + ((size_t)hk * S + s) * DH;
    float x[8], y[8];
    #pragma unroll
    for (int j = 0; j < 8; j += 4) {
      *(float4*)&x[j] = *(const float4*)(src + c0 + j);
      *(float4*)&y[j] = *(const float4*)(src + c0 + 64 + j);
    }
    u16 lo[8], hb[8];
    #pragma unroll
    for (int j = 0; j < 8; ++j) {
      float iv = __builtin_amdgcn_exp2f(-NFREQ * (float)(c0 + j));
      float sv, cv; __sincosf(pos * iv, &sv, &cv);
      if (hk == 0) Tab[(size_t)s * 64 + c0 + j] = make_float2(cv, sv);
      lo[j] = f2bf(x[j] * cv - y[j] * sv);
      hb[j] = f2bf(y[j] * cv + x[j] * sv);
    }
    *(int4*)(dst + c0)      = *(int4*)&lo[0];
    *(int4*)(dst + c0 + 64) = *(int4*)&hb[0];
  }
  {
    const int r = tid >> 3, c = (tid & 7) * 16;
    const float* src = Vg + ((size_t)(s0 + r) * HKV + hk) * DH + c;
    #pragma unroll
    for (int j = 0; j < 16; j += 4) *(float4*)&T[r][c + j] = *(const float4*)(src + j);
  }
  __syncthreads();
  {
    const int d = tid >> 1, hf = (tid & 1) * 16;
    u16 buf[16];
    #pragma unroll
    for (int i = 0; i < 16; ++i) buf[i] = f2bf(T[hf + i][d]);
    u16* dst = Vt + ((size_t)hk * DH + d) * S + s0 + hf;
    *(int4*)(dst)     = *(int4*)&buf[0];
    *(int4*)(dst + 8) = *(int4*)&buf[8];
  }
}

// Register prefetch of next KV tile. NAMED scalars (no arrays/lambdas: alloca trap).
// 512 threads: K tile 64x128 (tid>>3 row, 2x int4), V tile 128x64 (tid>>2 row, 2x int4).
#define LOAD_KV(kv0_) do {                                                 \
    const int4* ks_ = (const int4*)(Kb + (size_t)((kv0_) + kr) * DH + kc); \
    fk0 = ks_[0]; fk1 = ks_[1];                                            \
    const int4* vs_ = (const int4*)(Vb + (kv0_));                          \
    fv0 = vs_[0]; fv1 = vs_[1];                                            \
  } while (0)

#define STORE_KV() do {                                                    \
    *(int4*)&Ks[kr][kc]     = fk0; *(int4*)&Ks[kr][kc + 8] = fk1;          \
    *(int4*)&Vs[vd][vc]     = fv0; *(int4*)&Vs[vd][vc + 8] = fv1;          \
  } while (0)

// ---------- main: flash attention, S^T/O^T, 16 q-rows per wave (16x16x32 MFMA) ----------
// 8 waves / 128 q-rows per block, grid 32x17 = 544 blocks -> whole grid co-resident
// (~2.1 blocks/CU, reg-limited 2 blocks = 16 waves/CU = 50% cap vs old 37.5%).
// LDS 54272 B: Ks 17408 + Vs 18432 + Ps 18432 (Q prologue overlays Ks+Vs region).
// Ps C->B transform via wave-private LDS b64 writes (2-way, conflict-free; the old
// u32 scatter was 4-way = the bulk of the 5.18M SQ_LDS_BANK_CONFLICT).
__global__ __launch_bounds__(512, 4)
void attn_main(const float* __restrict__ Qg, const u16* __restrict__ Kr,
               const u16* __restrict__ Vt, const float2* __restrict__ Tab,
               float* __restrict__ Og, int S) {
  const int h = blockIdx.x;
  const int nqb = gridDim.y;
  const int q0 = (nqb - 1 - (int)blockIdx.y) * 128;   // heavy blocks first
  const int hk = h >> 2;
  const int tid = threadIdx.x;
  const int lane = tid & 63;
  const int wave = tid >> 6;       // 0..7
  const int qid  = lane & 15;      // q col within wave tile (C/D n-index)
  const int quad = lane >> 4;      // 0..3
  const int k8   = quad * 8;       // A/B-frag k offset within a 32-chunk

  __shared__ __align__(16) char smem[54272];
  u16 (*Qs)[136] = (u16(*)[136])smem;            // 128 x 136 (prologue overlay)
  u16 (*Ks)[136] = (u16(*)[136])smem;            // 64 x 136
  u16 (*Vs)[72]  = (u16(*)[72])(smem + 17408);   // 128 x 72
  u16 (*Ps)[72]  = (u16(*)[72])(smem + 35840);   // 128 x 72, row = wave*16 + q

  const u16* Kb = Kr + (size_t)hk * S * DH;
  const int kr = tid >> 3, kc = (tid & 7) * 16;
  const int vd = tid >> 2, vc = (tid & 3) * 16;
  const u16* Vb = Vt + ((size_t)hk * DH + vd) * S + vc;

  int4 fk0, fk1, fv0, fv1;
  LOAD_KV(0);   // tile-0 loads fly during the Q prologue

  // ---- prologue: stage Q (128 rows) with table-RoPE * QSCALE ----
  {
    const int r = tid >> 2, c0 = (tid & 3) * 16;
    const int s = q0 + r;
    const float* qrow = Qg + ((size_t)s * HQ + h) * DH;
    const float2* tb = Tab + (size_t)s * 64 + c0;
    float x[16], y[16];
    float2 t[16];
    #pragma unroll
    for (int j = 0; j < 16; j += 4) {
      *(float4*)&x[j] = *(const float4*)(qrow + c0 + j);
      *(float4*)&y[j] = *(const float4*)(qrow + c0 + 64 + j);
    }
    #pragma unroll
    for (int j = 0; j < 16; j += 2) *(float4*)&t[j] = *(const float4*)(tb + j);
    u16 lo[16], hb[16];
    #pragma unroll
    for (int j = 0; j < 16; ++j) {
      lo[j] = f2bf((x[j] * t[j].x - y[j] * t[j].y) * QSCALE);
      hb[j] = f2bf((y[j] * t[j].x + x[j] * t[j].y) * QSCALE);
    }
    *(int4*)(&Qs[r][c0])      = *(int4*)&lo[0];
    *(int4*)(&Qs[r][c0 + 8])  = *(int4*)&lo[8];
    *(int4*)(&Qs[r][c0 + 64]) = *(int4*)&hb[0];
    *(int4*)(&Qs[r][c0 + 72]) = *(int4*)&hb[8];
  }
  __syncthreads();
  const int qw0 = q0 + wave * 16;
  const int q   = qw0 + qid;          // this lane's q row
  bf16x8 qa[4];                       // B-frags: Q[q][32c + k8 + j]
  {
    const u16* qb = &Qs[wave * 16 + qid][k8];
    #pragma unroll
    for (int c = 0; c < 4; ++c) qa[c] = *(const bf16x8*)(qb + 32 * c);
  }
  __syncthreads();   // Qs dead; region becomes Ks/Vs
  STORE_KV();        // tile 0 -> LDS
  __syncthreads();

  int wstart = q0 - WIN; if (wstart < META) wstart = META;
  int nwin = (q0 + 128 - wstart) >> 6; if (nwin < 0) nwin = 0;
  const int ntiles = 2 + nwin;        // meta tiles first

  f32x4 acc[8];                       // O^T: acc[D], d = 16D + 4*quad + r, col q
  #pragma unroll
  for (int D = 0; D < 8; ++D)
    #pragma unroll
    for (int r = 0; r < 4; ++r) acc[D][r] = 0.f;
  float m_i = -1e30f, l_i = 0.f;      // l_i is a quad-partial; combined in epilogue

  for (int t = 0; t < ntiles; ++t) {
    const int kv0 = (t < 2) ? t * 64 : wstart + (t - 2) * 64;
    const bool haveNext = (t + 1 < ntiles);
    if (haveNext) {
      const int kvn = (t + 1 < 2) ? (t + 1) * 64 : wstart + (t - 1) * 64;
      LOAD_KV(kvn);
    }

    const bool active = (kv0 <= qw0 + 15) &&
                        ((kv0 < META) || (qw0 - kv0 - 63 <= WIN));
    if (active) {
      // ---- S^T = K Q^T : 4 16x16 C-tiles over kv, K=128 in 4 chunks ----
      f32x4 sv[4];
      #pragma unroll
      for (int T = 0; T < 4; ++T)
        #pragma unroll
        for (int r = 0; r < 4; ++r) sv[T][r] = 0.f;
      #pragma unroll
      for (int T = 0; T < 4; ++T) {
        const u16* ka = &Ks[16 * T + qid][k8];
        #pragma unroll
        for (int c = 0; c < 4; ++c)
          sv[T] = __builtin_amdgcn_mfma_f32_16x16x32_bf16(
                    *(const bf16x8*)(ka + 32 * c), qa[c], sv[T], 0, 0, 0);
      }

      // ---- mask (per element: kv = kv0 + 16T + 4*quad + r) ----
      const bool fullv = (kv0 + 63 <= qw0) &&
                         ((kv0 + 63 < META) || (qw0 + 15 - kv0 <= WIN));
      if (!fullv) {
        #pragma unroll
        for (int T = 0; T < 4; ++T) {
          #pragma unroll
          for (int r = 0; r < 4; ++r) {
            const int kv = kv0 + 16 * T + 4 * quad + r;
            if (!((kv <= q) && (((q - kv) <= WIN) || (kv < META)))) sv[T][r] = -1e30f;
          }
        }
      }

      // ---- online softmax: reg reduce + 2 cross-quad shuffles for max ----
      float mx = -1e30f;
      #pragma unroll
      for (int T = 0; T < 4; ++T)
        #pragma unroll
        for (int r = 0; r < 4; ++r) mx = fmaxf(mx, sv[T][r]);
      mx = fmaxf(mx, __shfl_xor(mx, 16));
      mx = fmaxf(mx, __shfl_xor(mx, 32));
      const float mnew = fmaxf(m_i, mx);
      const float al = __builtin_amdgcn_exp2f(m_i - mnew);
      m_i = mnew;
      float ps = 0.f;
      #pragma unroll
      for (int T = 0; T < 4; ++T)
        #pragma unroll
        for (int r = 0; r < 4; ++r) {
          sv[T][r] = __builtin_amdgcn_exp2f(sv[T][r] - mnew);
          ps += sv[T][r];
        }
      l_i = l_i * al + ps;            // quad-partial sum (m shared => consistent)
      #pragma unroll
      for (int D = 0; D < 8; ++D)
        #pragma unroll
        for (int r = 0; r < 4; ++r) acc[D][r] *= al;

      // ---- P: C-layout -> B-layout via wave-private LDS (in-order, no barrier) ----
      // b64 writes: banks 4*qid + 2*quad (mod 32) -> 2 lanes/bank-pair = conflict-free
      {
        int2* pw = (int2*)&Ps[wave * 16 + qid][0];
        #pragma unroll
        for (int T = 0; T < 4; ++T) {
          int2 pr;
          pr.x = (int)packbf(sv[T][0], sv[T][1]);
          pr.y = (int)packbf(sv[T][2], sv[T][3]);
          pw[4 * T + quad] = pr;
        }
      }
      const u16* pb = &Ps[wave * 16 + qid][k8];
      const bf16x8 p0 = *(const bf16x8*)(pb);        // kv chunk 0 (0..31)
      const bf16x8 p1 = *(const bf16x8*)(pb + 32);   // kv chunk 1 (32..63)

      // ---- O^T += V^T P^T : 8 d-tiles x 2 kv-chunks ----
      #pragma unroll
      for (int D = 0; D < 8; ++D) {
        const u16* va = &Vs[16 * D + qid][k8];
        acc[D] = __builtin_amdgcn_mfma_f32_16x16x32_bf16(*(const bf16x8*)(va),      p0, acc[D], 0, 0, 0);
        acc[D] = __builtin_amdgcn_mfma_f32_16x16x32_bf16(*(const bf16x8*)(va + 32), p1, acc[D], 0, 0, 0);
      }
    }

    if (haveNext) {
      __syncthreads();   // all waves done reading Ks/Vs
      STORE_KV();        // prefetched tile -> LDS
      __syncthreads();
    }
  }

  // ---- epilogue: combine quad-partial l, scale, 16B stores ----
  l_i += __shfl_xor(l_i, 16);
  l_i += __shfl_xor(l_i, 32);
  const float inv = 1.0f / l_i;
  float* ob = Og + ((size_t)q * HQ + h) * DH;
  #pragma unroll
  for (int D = 0; D < 8; ++D) {       // d = 16D + 4*quad + {0..3}
    float4 o = { acc[D][0] * inv, acc[D][1] * inv, acc[D][2] * inv, acc[D][3] * inv };
    *(float4*)(ob + 16 * D + 4 * quad) = o;
  }
}

extern "C" void kernel_launch(void* const* d_in, const int* in_sizes, int n_in,
                              void* d_out, int out_size, void* d_ws, size_t ws_size,
                              hipStream_t stream) {
  const float* Qg = (const float*)d_in[0];
  const float* Kg = (const float*)d_in[1];
  const float* Vg = (const float*)d_in[2];
  float* Og = (float*)d_out;
  const int S = in_sizes[0] / (HQ * DH);   // 2176

  u16* Kr = (u16*)d_ws;                                           // 4.45 MB
  u16* Vt = (u16*)((char*)d_ws + (size_t)HKV * S * DH * 2);       // 4.45 MB
  float2* Tab = (float2*)((char*)d_ws + (size_t)HKV * S * DH * 4); // 1.11 MB cos/sin table

  prep_kv<<<dim3(HKV, S / 32), dim3(256), 0, stream>>>(Kg, Vg, Kr, Vt, Tab, S);
  attn_main<<<dim3(HQ, S / 128), dim3(512), 0, stream>>>(Qg, Kr, Vt, Tab, Og, S);
}